// Round 4
// baseline (230.270 us; speedup 1.0000x reference)
//
#include <hip/hip_runtime.h>

#define NBINS 256
#define NCH 3
#define NHIST (2 * NCH * NBINS)   // 1536 global bins (input + label)
#define HW4 65536                  // 512*512/4 float4s per (batch,channel) plane
#define BATCH 32
#define BLOCKS_PER_JOB 256         // 256 blk * 256 thr = 65536 threads = HW4 exactly
#define THREADS 256

// ===========================================================================
// R11: layout experiment — contiguous-per-lane histogram regions.
// The 2x2: {bank=lane (conflict-free), rows=bin-scattered} vs
//          {bank=bin (random ~5-way conflicts), rows=lane-stable}.
// R3 used the first at ~30 cyc/scattered-wave-op despite 0 bank conflicts
// (5.2x the 5.8-cyc conflict-free ds_read baseline) — suggesting the cost is
// address-divergence (row phasing), not banks. This kernel tests the second
// cell: lane region = 64 contiguous words (256 B), word = lane*64 + (bin>>2).
// Lane-private words -> non-atomic RMW still race-free. Expected per m136:
// ~5-6-way max bank multiplicity ~ 2.2x baseline ~ 13 cyc/op < 30.
// batch4 register dedup kept (R10 showed wider dedup is VALU-bound).
// Per-thread per-bin count <= 128 < 255: u8 safe.
// ===========================================================================

__device__ __forceinline__ void batch4(unsigned int* lbase, float4 v) {
    const int b0 = (int)fminf(fmaxf(v.x, 0.f), 255.f);  // trunc==floor, v>=0
    const int b1 = (int)fminf(fmaxf(v.y, 0.f), 255.f);
    const int b2 = (int)fminf(fmaxf(v.z, 0.f), 255.f);
    const int b3 = (int)fminf(fmaxf(v.w, 0.f), 255.f);
    const int w0 = b0 >> 2, w1 = b1 >> 2, w2 = b2 >> 2, w3 = b3 >> 2;
    unsigned int i0 = 1u << ((b0 & 3) << 3);
    unsigned int i1 = 1u << ((b1 & 3) << 3);
    unsigned int i2 = 1u << ((b2 & 3) << 3);
    unsigned int i3 = 1u << ((b3 & 3) << 3);
    unsigned int* const p0 = lbase + w0;   // contiguous region: word = w
    unsigned int* const p1 = lbase + w1;
    unsigned int* const p2 = lbase + w2;
    unsigned int* const p3 = lbase + w3;
    const unsigned int r0 = *p0;
    const unsigned int r1 = *p1;
    const unsigned int r2 = *p2;
    const unsigned int r3 = *p3;
    if (w0 == w1) { i1 += i0; i0 = 0; }
    if (w0 == w2) { i2 += i0; i0 = 0; }
    if (w0 == w3) { i3 += i0; i0 = 0; }
    if (w1 == w2) { i2 += i1; i1 = 0; }
    if (w1 == w3) { i3 += i1; i1 = 0; }
    if (w2 == w3) { i3 += i2; i2 = 0; }
    *p0 = r0 + i0;
    *p1 = r1 + i1;
    *p2 = r2 + i2;
    *p3 = r3 + i3;
}

__global__ __launch_bounds__(THREADS) void hist_kernel(
    const float* __restrict__ a, const float* __restrict__ b,
    unsigned int* __restrict__ gh) {
    __shared__ unsigned int sh[16384];  // 64 KB: 256 regions x 64 words (u8x4)
    const int tid  = threadIdx.x;

    uint4* shv = (uint4*)sh;
    #pragma unroll
    for (int i = 0; i < 16; ++i)
        shv[tid + i * THREADS] = make_uint4(0u, 0u, 0u, 0u);
    __syncthreads();

    const int job        = blockIdx.x >> 8;        // 0..5
    const int blockInJob = blockIdx.x & 255;
    const int arr = job / NCH;   // 0 = input, 1 = label
    const int ch  = job % NCH;

    const float4* __restrict__ src = (const float4*)(arr ? b : a);
    // Region for thread tid: 64 contiguous words (256 B) = 2 LDS rows.
    // bank = (bin>>2)&31 (random over bins); rows lane-stable.
    unsigned int* const lbase = &sh[tid << 6];
    const unsigned pos = ((unsigned)blockInJob << 8) | (unsigned)tid;  // 0..65535

    // 8 iterations x 4 float4 loads: all 4 loads issued before any DS work.
    for (int it = 0; it < BATCH / 4; ++it) {
        const int bt = it << 2;
        const float4 v0 = src[(unsigned)(((bt + 0) * NCH + ch) << 16) | pos];
        const float4 v1 = src[(unsigned)(((bt + 1) * NCH + ch) << 16) | pos];
        const float4 v2 = src[(unsigned)(((bt + 2) * NCH + ch) << 16) | pos];
        const float4 v3 = src[(unsigned)(((bt + 3) * NCH + ch) << 16) | pos];
        batch4(lbase, v0);
        batch4(lbase, v1);
        batch4(lbase, v2);
        batch4(lbase, v3);
    }
    __syncthreads();

    // Flush: thread t owns bin t; sums byte (t&3) of word r*64 + (t>>2) over
    // all 256 regions r. Quad-uniform r-swizzle: the 4 threads sharing grp
    // read the SAME word each step (broadcast, free); the 16 grps of a wave
    // map to 16 distinct banks (word % 32 == grp & 31) -> conflict-free.
    unsigned int sum = 0;
    const unsigned char* shb = (const unsigned char*)sh;
    const int grp = tid >> 2;          // bin>>2 : word offset within region
    const int boff = tid & 3;          // byte within word
    #pragma unroll 8
    for (int r0 = 0; r0 < 256; ++r0) {
        const int r = (r0 + grp) & 255;
        sum += shb[((((r << 6) + grp) << 2) | boff)];
    }
    atomicAdd(&gh[(arr * NCH + ch) * NBINS + tid], sum);
}

// ---------------------------------------------------------------------------
// Bhattacharyya kernel: 1 block x 256 threads, fp64 reduction. (unchanged)
// ---------------------------------------------------------------------------
__device__ __forceinline__ double block_reduce256(double v, double* sh4) {
    const int t = threadIdx.x;
    const int lane = t & 63, w = t >> 6;
    #pragma unroll
    for (int o = 32; o > 0; o >>= 1) v += __shfl_down(v, o, 64);
    if (lane == 0) sh4[w] = v;
    __syncthreads();
    double r = sh4[0] + sh4[1] + sh4[2] + sh4[3];
    __syncthreads();
    return r;
}

__global__ __launch_bounds__(256) void bhat_kernel(
    const unsigned int* __restrict__ gh, float* __restrict__ out) {
    __shared__ double sh4[4];
    const int t = threadIdx.x;  // bin index
    double result = 0.0;
    #pragma unroll
    for (int ch = 0; ch < NCH; ++ch) {
        const double h1 = (double)gh[ch * NBINS + t];
        const double h2 = (double)gh[(NCH + ch) * NBINS + t];
        const double s  = block_reduce256(sqrt(h1 * h2), sh4);
        const double s1 = block_reduce256(h1, sh4);
        const double s2 = block_reduce256(h2, sh4);
        const double denom = sqrt((s1 / (double)NBINS) * (s2 / (double)NBINS)) * (double)NBINS;
        const double v = 1.0 - s / denom;
        result += sqrt(v > 0.0 ? v : 0.0);
    }
    if (t == 0) out[0] = (float)result;
}

extern "C" void kernel_launch(void* const* d_in, const int* in_sizes, int n_in,
                              void* d_out, int out_size, void* d_ws, size_t ws_size,
                              hipStream_t stream) {
    const float* input = (const float*)d_in[0];
    const float* label = (const float*)d_in[1];
    float* out = (float*)d_out;
    unsigned int* gh = (unsigned int*)d_ws;

    // d_ws is poisoned with 0xAA before every timed launch — zero the hists.
    hipMemsetAsync(gh, 0, NHIST * sizeof(unsigned int), stream);

    hist_kernel<<<6 * BLOCKS_PER_JOB, THREADS, 0, stream>>>(input, label, gh);
    bhat_kernel<<<1, 256, 0, stream>>>(gh, out);
}